// Round 1
// 520.502 us; speedup vs baseline: 1.1634x; 1.1634x over previous
//
#include <hip/hip_runtime.h>
#include <math.h>

// Pipeline (float-input dtype auto-detected bf16 vs fp32; internal fp64/fp32/bf16):
//  0. detect     : 1 wave inspects pentachora u16 exponent fields -> flag (1=bf16 inputs, 0=fp32)
//  0b prep_x     : x -> bf16 xb[4096][512]
//  0c transpose_w: Wqkv->Wt1[1536][512] bf16 and Wout->Wt2[512][512] bf16, one combined launch
//  1. penta_sums : TOKEN-SPARSE — only the <=2048 vocab rows named by token_ids are consumed
//                  downstream, so compute 15 fp64 sums per TOKEN SLOT (not per vocab entry).
//                  Cuts stage-1 HBM read 327.7 MB -> ~21 MB (dups are cache hits).
//  2. coords     : fp64 unrolled no-pivot Cayley-Menger det (fixed row0/1 swap; pivots ~ -1024,
//                  safe — and sigmoid(10V) saturates to 1.0 anyway) + stats + cantor -> ctok[i]
//                  directly (2048 threads; the old vocab-wide ci + gather kernel are gone)
//  4. routes     : integer-distance histogram top-64, parallel scans, tie-break lowest index
//  5. gemm qkv   : LDS-free direct-global bf16 MFMA (A[M,K] row frag, Wt[N,K] row frag)
//  6. attn       : 4 queries/block (1/wave); k-phase COALESCED row loads + 8-lane-group
//                  shfl reduce; v-phase coalesced; fp32 softmax -> bf16
//  7. gemm out   : same direct GEMM -> d_out (dtype per flag)

typedef unsigned short u16;
typedef short short8 __attribute__((ext_vector_type(8)));
typedef u16 u16x8 __attribute__((ext_vector_type(8)));
typedef float floatx4 __attribute__((ext_vector_type(4)));

#define NVOCAB 32000
#define NSEQ 2048

__device__ inline float b2f(u16 u){
  union{unsigned int i; float f;} x; x.i = ((unsigned int)u)<<16; return x.f;
}
__device__ inline u16 f2b(float f){
  union{float f; unsigned int u;} x; x.f = f;
  unsigned int u = x.u;
  u += 0x7fffu + ((u >> 16) & 1u);   // RNE
  return (u16)(u >> 16);
}
__device__ inline double shfl_xor_d(double v, int m){
  union{double d; int i[2];} x; x.d = v;
  x.i[0] = __shfl_xor(x.i[0], m, 64);
  x.i[1] = __shfl_xor(x.i[1], m, 64);
  return x.d;
}

// ---------------- Stage 0: input dtype detection ----------------
__global__ void detect_kernel(const u16* __restrict__ p, int* __restrict__ flag){
  int lane = threadIdx.x;
  u16 u = p[lane*2];
  int e = (u >> 7) & 0xff;
  bool pass = (e >= 96 && e <= 144);
  unsigned long long m = __ballot(pass);
  if (lane == 0) *flag = (m == ~0ull) ? 1 : 0;
}

// ---------------- Stage 0b: x -> bf16 (8 elements/thread) ----------------
__global__ __launch_bounds__(256) void prep_x_kernel(const void* __restrict__ x,
                                                     const int* __restrict__ flagp,
                                                     u16* __restrict__ xb){
  int f = *flagp;
  size_t i = ((size_t)blockIdx.x*256 + threadIdx.x)*8;
  if (f){
    *(u16x8*)(xb+i) = *(const u16x8*)((const u16*)x + i);
  } else {
    const float* xf = (const float*)x + i;
    float4 a = *(const float4*)xf;
    float4 b = *(const float4*)(xf+4);
    u16x8 o;
    o[0]=f2b(a.x); o[1]=f2b(a.y); o[2]=f2b(a.z); o[3]=f2b(a.w);
    o[4]=f2b(b.x); o[5]=f2b(b.y); o[6]=f2b(b.z); o[7]=f2b(b.w);
    *(u16x8*)(xb+i) = o;
  }
}

// ---------------- Stage 0c: combined W[K][N] -> Wt[N][K] bf16 (K=512) ----------------
__global__ __launch_bounds__(256) void transpose_w_kernel(const void* __restrict__ W1,
                                                          const void* __restrict__ W2,
                                                          u16* __restrict__ Wt1,
                                                          u16* __restrict__ Wt2,
                                                          const int* __restrict__ flagp){
  int f = *flagp;
  __shared__ u16 tile[32][33];
  const int K = 512;
  int bx = blockIdx.x, k0 = blockIdx.y*32;
  const void* W; u16* Wt; int N, n0;
  if (bx < 48){ W = W1; Wt = Wt1; N = 1536; n0 = bx*32; }
  else        { W = W2; Wt = Wt2; N = 512;  n0 = (bx-48)*32; }
  int tx = threadIdx.x & 31, ty = threadIdx.x >> 5;
  #pragma unroll
  for (int i=0;i<32;i+=8){
    int k = k0+ty+i, n = n0+tx;
    u16 v = f ? ((const u16*)W)[(size_t)k*N + n]
              : f2b(((const float*)W)[(size_t)k*N + n]);
    tile[ty+i][tx] = v;
  }
  __syncthreads();
  #pragma unroll
  for (int i=0;i<32;i+=8){
    Wt[(size_t)(n0+ty+i)*K + k0+tx] = tile[tx][ty+i];
  }
}

// ---------------- Stage 1: per-TOKEN pair/centroid sums (fp64), wave per token slot ----------------
__global__ __launch_bounds__(256) void penta_sums_kernel(const void* __restrict__ penta,
                                                         const int* __restrict__ flagp,
                                                         const int* __restrict__ tok,
                                                         double* __restrict__ sums){
  int f = *flagp;
  int slot = blockIdx.x*4 + (threadIdx.x>>6);   // token slot, 4 waves/block
  int w = tok[slot];                            // vocab row for this token
  int lane = threadIdx.x & 63;
  float pf[5][8];
  if (f){   // bf16 inputs
    const u16* base = (const u16*)penta + (size_t)w*2560 + lane*8;
    #pragma unroll
    for (int i=0;i<5;i++){
      u16x8 u = *(const u16x8*)(base + i*512);
      #pragma unroll
      for (int j=0;j<8;j++) pf[i][j] = b2f(u[j]);
    }
  } else {  // fp32 inputs
    const float* base = (const float*)penta + (size_t)w*2560 + lane*8;
    #pragma unroll
    for (int i=0;i<5;i++){
      float4 f0 = *(const float4*)(base + i*512);
      float4 f1 = *(const float4*)(base + i*512 + 4);
      pf[i][0]=f0.x; pf[i][1]=f0.y; pf[i][2]=f0.z; pf[i][3]=f0.w;
      pf[i][4]=f1.x; pf[i][5]=f1.y; pf[i][6]=f1.z; pf[i][7]=f1.w;
    }
  }
  double acc[15];
  #pragma unroll
  for (int k=0;k<15;k++) acc[k]=0.0;
  #pragma unroll
  for (int j=0;j<8;j++){
    double p[5];
    #pragma unroll
    for (int i=0;i<5;i++) p[i] = (double)pf[i][j];
    double mean = (p[0]+p[1]+p[2]+p[3]+p[4])*0.2;
    int idx=0;
    #pragma unroll
    for (int a=0;a<5;a++)
      #pragma unroll
      for (int b=a+1;b<5;b++){ double d=p[a]-p[b]; acc[idx++] += d*d; }
    #pragma unroll
    for (int i=0;i<5;i++){ double d=p[i]-mean; acc[10+i] += d*d; }
  }
  #pragma unroll
  for (int k=0;k<15;k++){
    double s = acc[k];
    for (int off=32; off; off>>=1) s += shfl_xor_d(s, off);
    acc[k]=s;
  }
  if (lane==0){
    double* o = sums + (size_t)slot*15;
    #pragma unroll
    for (int k=0;k<15;k++) o[k]=acc[k];
  }
}

// ---------------- Stage 2: fp64 unrolled det + stats + cantor, one thread per token slot ----------------
__global__ __launch_bounds__(256) void coords_kernel(const double* __restrict__ sums,
                                                     int* __restrict__ ctok){
  int v = blockIdx.x*256 + threadIdx.x;
  if (v >= NSEQ) return;
  const double* s = sums + (size_t)v*15;
  double ds[10], cd2[5];
  #pragma unroll
  for (int k=0;k<10;k++) ds[k]=s[k];
  #pragma unroll
  for (int k=0;k<5;k++) cd2[k]=s[10+k];
  // Cayley-Menger with rows 0,1 pre-swapped: S[0]=[1,0,d01..], S[1]=[0,1,1,1,1,1].
  // det(M_orig) = -det(S); volume^2 = -det(M)/9216 = det(S)/9216.
  // No pivoting needed: pivot0=1, pivot1=1, later pivots ~ -1024 (dist_sq ~ 2*512).
  double M[6][6];
  M[0][0]=1.0; M[0][1]=0.0; M[0][2]=ds[0]; M[0][3]=ds[1]; M[0][4]=ds[2]; M[0][5]=ds[3];
  M[1][0]=0.0; M[1][1]=1.0; M[1][2]=1.0;   M[1][3]=1.0;   M[1][4]=1.0;   M[1][5]=1.0;
  M[2][0]=1.0; M[2][1]=ds[0]; M[2][2]=0.0;   M[2][3]=ds[4]; M[2][4]=ds[5]; M[2][5]=ds[6];
  M[3][0]=1.0; M[3][1]=ds[1]; M[3][2]=ds[4]; M[3][3]=0.0;   M[3][4]=ds[7]; M[3][5]=ds[8];
  M[4][0]=1.0; M[4][1]=ds[2]; M[4][2]=ds[5]; M[4][3]=ds[7]; M[4][4]=0.0;   M[4][5]=ds[9];
  M[5][0]=1.0; M[5][1]=ds[3]; M[5][2]=ds[6]; M[5][3]=ds[8]; M[5][4]=ds[9]; M[5][5]=0.0;
  double det=1.0;
  #pragma unroll
  for (int c=0;c<6;c++){
    double pv = M[c][c];
    det *= pv;
    double inv = 1.0/pv;
    #pragma unroll
    for (int r=c+1;r<6;r++){
      double fq = M[r][c]*inv;
      #pragma unroll
      for (int cc=c+1;cc<6;cc++) M[r][cc] -= fq*M[c][cc];
    }
  }
  double volume = sqrt(fmax(det/9216.0, 0.0));
  double vn = 1.0/(1.0+exp(-10.0*volume));
  double me=0.0, e[10];
  #pragma unroll
  for (int k=0;k<10;k++){ e[k]=sqrt(ds[k]); me+=e[k]; }
  me *= 0.1;
  double var=0.0;
  #pragma unroll
  for (int k=0;k<10;k++){ double d=e[k]-me; var+=d*d; }
  double se = sqrt(var/9.0);                    // ddof=1
  double er = 1.0/(1.0+exp(-(se/(me+1e-6))));
  double mc=0.0, cd[5];
  #pragma unroll
  for (int k=0;k<5;k++){ cd[k]=sqrt(cd2[k]); mc+=cd[k]; }
  mc *= 0.2;
  double v2=0.0;
  #pragma unroll
  for (int k=0;k<5;k++){ double d=cd[k]-mc; v2+=d*d; }
  double sp = sqrt(v2/4.0);                     // ddof=1
  double sn = 1.0/(1.0+exp(-sp));
  const double EPSd = 1e-6;
  double x = 0.4*vn + 0.3*er + 0.3*sn;
  x = fmin(fmax(x, EPSd), 1.0-EPSd);
  double bump = (vn+er+sn)*0.01;
  double cv=0.0, factor=0.5;
  #pragma unroll
  for (int it=0; it<8; it++){
    double xs = x*3.0;
    double frac = xs - floor(xs);
    if (xs >= 2.0) cv += factor;
    x = fmin(fmax(frac + bump, EPSd), 1.0-EPSd);
    factor *= 0.5;
  }
  cv = fmin(fmax(cv,0.0),1.0);
  ctok[v] = (int)(cv*256.0 + 0.5);              // exact multiple of 1/256 -> exact int (max 255)
}

// ---------------- Stage 4: top-64 neighbors by integer coord distance ----------------
__global__ __launch_bounds__(256) void routes_kernel(const int* __restrict__ ctok,
                                                     int* __restrict__ routes){
  __shared__ int cs[NSEQ];
  __shared__ int hist[256];
  __shared__ int scn[256];
  __shared__ int cnts[256];
  __shared__ int params[3];   // T, need, out-counter
  int tid = threadIdx.x;
  int q = blockIdx.x;
  for (int j=tid; j<NSEQ; j+=256) cs[j] = ctok[j];
  hist[tid] = 0;
  if (tid==0) params[2]=0;
  __syncthreads();
  int cq = cs[q];
  int base = tid*8;
  int dloc[8];
  #pragma unroll
  for (int i=0;i<8;i++){
    int d = cs[base+i] - cq; d = d<0 ? -d : d;
    dloc[i] = d;
    atomicAdd(&hist[d], 1);
  }
  __syncthreads();
  // parallel inclusive scan of hist -> scn
  scn[tid] = hist[tid];
  __syncthreads();
  #pragma unroll
  for (int off=1; off<256; off<<=1){
    int cur = scn[tid];
    int add = (tid>=off) ? scn[tid-off] : 0;
    __syncthreads();
    scn[tid] = cur + add;
    __syncthreads();
  }
  {
    int incl = scn[tid];
    int prev = (tid==0) ? 0 : scn[tid-1];
    if (incl >= 64 && prev < 64){ params[0]=tid; params[1]=64-prev; }
  }
  __syncthreads();
  int T=params[0], need=params[1];
  int ceq=0;
  #pragma unroll
  for (int i=0;i<8;i++) ceq += (dloc[i]==T) ? 1 : 0;
  // parallel scan of per-thread equal-counts -> exclusive rank base
  cnts[tid]=ceq;
  __syncthreads();
  #pragma unroll
  for (int off=1; off<256; off<<=1){
    int cur = cnts[tid];
    int add = (tid>=off) ? cnts[tid-off] : 0;
    __syncthreads();
    cnts[tid] = cur + add;
    __syncthreads();
  }
  int rank = cnts[tid] - ceq;
  int* rq = routes + q*64;
  #pragma unroll
  for (int i=0;i<8;i++){
    int d = dloc[i];
    bool sel = false;
    if (d < T) sel = true;
    else if (d == T){ sel = (rank < need); rank++; }
    if (sel){
      int pos = atomicAdd(&params[2], 1);
      rq[pos] = base + i;   // set semantics: order within the 64 doesn't matter for softmax
    }
  }
}

// ---------------- Stages 5/7: LDS-free direct-global bf16 MFMA GEMM ----------------
template<int C_FOLLOW>
__global__ __launch_bounds__(256) void gemm_direct(const u16* __restrict__ A,
    const u16* __restrict__ Wt, const void* __restrict__ bias, void* __restrict__ Cout,
    const int* __restrict__ flagp, int M, int N, int K)
{
  int f = *flagp;
  bool c_bf16 = C_FOLLOW ? (f==1) : true;
  int tid = threadIdx.x;
  int wv = tid>>6, lane = tid&63, lr = lane&15, lq = lane>>4;
  int m0 = blockIdx.y<<6, n0 = blockIdx.x<<6;
  const u16* Arow = A  + (size_t)(m0 + (wv<<4) + lr)*K + (lq<<3);
  const u16* Wr0  = Wt + (size_t)(n0 + lr)*K + (lq<<3);
  size_t wstep = (size_t)16*K;
  floatx4 acc[4];
  #pragma unroll
  for (int t=0;t<4;t++) acc[t] = (floatx4){0.f,0.f,0.f,0.f};
  #pragma unroll 4
  for (int k0=0;k0<K;k0+=32){
    short8 af = *(const short8*)(Arow + k0);
    #pragma unroll
    for (int t4=0;t4<4;t4++){
      short8 bfv = *(const short8*)(Wr0 + (size_t)t4*wstep + k0);
      acc[t4] = __builtin_amdgcn_mfma_f32_16x16x32_bf16(af, bfv, acc[t4], 0, 0, 0);
    }
  }
  // C/D: row = lq*4 + r, col = lane&15
  #pragma unroll
  for (int t4=0;t4<4;t4++){
    #pragma unroll
    for (int r=0;r<4;r++){
      int m = m0 + (wv<<4) + (lq<<2) + r;
      int n = n0 + (t4<<4) + lr;
      float bv = f ? b2f(((const u16*)bias)[n]) : ((const float*)bias)[n];
      float val = acc[t4][r] + bv;
      if (c_bf16) ((u16*)Cout)[(size_t)m*N + n] = f2b(val);
      else        ((float*)Cout)[(size_t)m*N + n] = val;
    }
  }
}

// ---------------- Stage 6: gather attention, 4 queries/block (1 per wave) ----------------
// All memory phases use COALESCED full-row loads (1 KB per wave instruction):
//  k-phase: for each neighbor j, lane covers q/k dims [lane*8,lane*8+8); partial dot
//           reduced over the 8-lane head group via shfl_xor(1,2,4); score -> LDS.
//  softmax: lane=(h,jg) handles 8 scores of head h; group-reduce max/sum; probs -> LDS.
//  v-phase: lane=(h,dg) accumulates 8 output dims over j with coalesced v-row loads.
__global__ __launch_bounds__(256) void attn_kernel(const u16* __restrict__ qkv,
                                                   const int* __restrict__ routes,
                                                   u16* __restrict__ outa){
  __shared__ float sc[4][8*65];   // (65h+j)%32=(h+j)%32 -> conflict-free across heads
  __shared__ int rbuf[4][64];
  int tid = threadIdx.x;
  int wv = tid>>6, lane = tid&63;
  int bq = blockIdx.x*4 + wv;     // = b*2048 + q
  int b = bq >> 11;
  int q = bq & 2047;
  rbuf[wv][lane] = routes[(q<<6) + lane];
  int h8 = lane>>3;               // head this lane's dims belong to
  const u16* kb = qkv + (size_t)(b<<11)*1536;
  // my 8 q dims (coalesced 1KB load across the wave)
  float qv[8];
  {
    u16x8 qraw = *(const u16x8*)(kb + (size_t)q*1536 + lane*8);
    #pragma unroll
    for (int t=0;t<8;t++) qv[t] = b2f(qraw[t]);
  }
  __syncthreads();
  // k-phase
  for (int j=0;j<64;j++){
    int rj = rbuf[wv][j];
    u16x8 kraw = *(const u16x8*)(kb + (size_t)rj*1536 + 512 + lane*8);
    float p = 0.f;
    #pragma unroll
    for (int t=0;t<8;t++) p = fmaf(b2f(kraw[t]), qv[t], p);
    p += __shfl_xor(p, 1, 64);
    p += __shfl_xor(p, 2, 64);
    p += __shfl_xor(p, 4, 64);
    if ((lane&7)==0) sc[wv][h8*65 + j] = p * 0.125f;   // 1/sqrt(64)
  }
  __syncthreads();
  // softmax per head (8-lane group owns a head; each lane 8 scores)
  {
    int jg = (lane&7)<<3;
    float sv[8];
    float m = -1e30f;
    #pragma unroll
    for (int t=0;t<8;t++){ sv[t] = sc[wv][h8*65 + jg + t]; m = fmaxf(m, sv[t]); }
    m = fmaxf(m, __shfl_xor(m, 1, 64));
    m = fmaxf(m, __shfl_xor(m, 2, 64));
    m = fmaxf(m, __shfl_xor(m, 4, 64));
    float s = 0.f;
    #pragma unroll
    for (int t=0;t<8;t++){ sv[t] = expf(sv[t]-m); s += sv[t]; }
    s += __shfl_xor(s, 1, 64);
    s += __shfl_xor(s, 2, 64);
    s += __shfl_xor(s, 4, 64);
    float inv = 1.f/s;
    #pragma unroll
    for (int t=0;t<8;t++) sc[wv][h8*65 + jg + t] = sv[t]*inv;
  }
  __syncthreads();
  // v-phase: lane=(h8, dg) accumulates out dims [h8*64+dg, +8)
  int dg = (lane&7)<<3;
  const u16* vb = kb + 1024 + (h8<<6) + dg;
  float acc8[8];
  #pragma unroll
  for (int t=0;t<8;t++) acc8[t]=0.f;
  for (int j=0;j<64;j++){
    float p = sc[wv][h8*65 + j];
    u16x8 v8 = *(const u16x8*)(vb + (size_t)rbuf[wv][j]*1536);
    #pragma unroll
    for (int t=0;t<8;t++) acc8[t] = fmaf(p, b2f(v8[t]), acc8[t]);
  }
  u16x8 o;
  #pragma unroll
  for (int t=0;t<8;t++) o[t] = f2b(acc8[t]);
  *(u16x8*)(outa + (size_t)bq*512 + (h8<<6) + dg) = o;
}

extern "C" void kernel_launch(void* const* d_in, const int* in_sizes, int n_in,
                              void* d_out, int out_size, void* d_ws, size_t ws_size,
                              hipStream_t stream) {
  const void* penta = d_in[0];   // [32000,5,512]
  const void* x     = d_in[1];   // [2,2048,512]
  const int*  tok   = (const int*)d_in[2];   // [2048]
  const void* Wqkv  = d_in[3];   // [512,1536]
  const void* bqkv  = d_in[4];   // [1536]
  const void* Wout  = d_in[5];   // [512,512]
  const void* bout  = d_in[6];   // [512]

  char* ws = (char*)d_ws;
  int*    flag   = (int*)   (ws + 128000);     // 4 B
  int*    ctok   = (int*)   (ws + 131072);     // 8192 B
  int*    routes = (int*)   (ws + 139264);     // 524288 B   (end 663552)
  double* sums   = (double*)(ws + 663552);     // 245760 B used (token-sparse)
  u16*    xb     = (u16*)   (ws + 4503552);    // 4194304 B  (end 8697856)
  u16*    Wt1    = (u16*)   (ws + 8697856);    // 1572864 B  (end 10270720)
  u16*    Wt2    = (u16*)   (ws + 10270720);   // 524288 B   (end 10795008)
  u16*    qkv    = (u16*)   (ws + 10795008);   // 12582912 B (end 23377920)
  u16*    attn   = (u16*)   (ws + 23377920);   // 4194304 B  (end 27572224 ~ 26.3 MB)

  detect_kernel<<<dim3(1), dim3(64), 0, stream>>>((const u16*)penta, flag);
  prep_x_kernel<<<dim3(1024), dim3(256), 0, stream>>>(x, flag, xb);
  transpose_w_kernel<<<dim3(64,16), dim3(256), 0, stream>>>(Wqkv, Wout, Wt1, Wt2, flag);
  penta_sums_kernel<<<dim3(512), dim3(256), 0, stream>>>(penta, flag, tok, sums);
  coords_kernel<<<dim3(8), dim3(256), 0, stream>>>(sums, ctok);
  routes_kernel<<<dim3(2048), dim3(256), 0, stream>>>(ctok, routes);
  gemm_direct<0><<<dim3(24,64), dim3(256), 0, stream>>>(xb, Wt1, bqkv, (void*)qkv, flag, 4096, 1536, 512);
  attn_kernel<<<dim3(1024), dim3(256), 0, stream>>>(qkv, routes, attn);
  gemm_direct<1><<<dim3(8,64), dim3(256), 0, stream>>>(attn, Wt2, bout, d_out, flag, 4096, 512, 512);
}